// Round 7
// baseline (1138.002 us; speedup 1.0000x reference)
//
#include <hip/hip_runtime.h>

typedef _Float16 half8 __attribute__((ext_vector_type(8)));
typedef _Float16 half4 __attribute__((ext_vector_type(4)));
typedef float f4 __attribute__((ext_vector_type(4)));

#define NBK 1024     // bucket table size (256 nodes/bucket, supports N<=262144)
#define NBLK 128     // blocks in hist/scatter passes (fixed edge chunking)

// ---------------- graph preprocessing (NO global atomics) ----------------

__global__ __launch_bounds__(256)
void k_bhist(const int* __restrict__ ei, int E, int chunk,
             int* __restrict__ hb) {
  __shared__ int hd[NBK], hs[NBK];
  int t = threadIdx.x, blk = blockIdx.x;
  for (int i = t; i < NBK; i += 256) { hd[i] = 0; hs[i] = 0; }
  __syncthreads();
  int start = blk * chunk, end = min(E, start + chunk);
  for (int i = start + t; i < end; i += 256) {
    int dst = ei[i];
    int src = ei[E + i];
    atomicAdd(&hd[dst >> 8], 1);
    atomicAdd(&hs[src >> 8], 1);
  }
  __syncthreads();
  for (int i = t; i < NBK; i += 256) {
    hb[blk * NBK + i] = hd[i];
    hb[(NBLK + blk) * NBK + i] = hs[i];
  }
}

__global__ void k_colscan(int* __restrict__ hb, int* __restrict__ totals) {
  int tid = blockIdx.x * 256 + threadIdx.x;      // 0..2047
  int* tab = hb + (tid >> 10) * (NBLK * NBK);
  int j = tid & (NBK - 1);
  int run = 0;
  for (int b = 0; b < NBLK; ++b) {
    int idx = b * NBK + j;
    int v = tab[idx];
    tab[idx] = run;
    run += v;
  }
  totals[tid] = run;
}

__global__ void k_bscan2(const int* __restrict__ totals, int* __restrict__ boffs,
                         int* __restrict__ soffs, int* __restrict__ offs,
                         int* __restrict__ ctrs, int N, int E) {
  __shared__ int s[NBK];
  int t = threadIdx.x;                            // 1024 threads
  if (t < 24) ctrs[t] = 0;                        // agg work-steal counters
  int v = totals[t];
  s[t] = v;
  __syncthreads();
  for (int off = 1; off < NBK; off <<= 1) {
    int x = (t >= off) ? s[t - off] : 0;
    __syncthreads();
    s[t] += x;
    __syncthreads();
  }
  boffs[t] = s[t] - v;
  if (t == NBK - 1) boffs[NBK] = s[t];
  __syncthreads();
  int v2 = totals[NBK + t];
  s[t] = v2;
  __syncthreads();
  for (int off = 1; off < NBK; off <<= 1) {
    int x = (t >= off) ? s[t - off] : 0;
    __syncthreads();
    s[t] += x;
    __syncthreads();
  }
  soffs[t] = s[t] - v2;
  if (t == NBK - 1) soffs[NBK] = s[t];
  if (t == 0) offs[N] = E;
}

__global__ __launch_bounds__(256)
void k_bscatter(const int* __restrict__ ei, int E, int chunk,
                const int* __restrict__ hb, const int* __restrict__ boffs,
                const int* __restrict__ soffs,
                unsigned long long* __restrict__ pairs,
                unsigned char* __restrict__ srcb) {
  __shared__ int based[NBK], posd[NBK], bases[NBK], poss[NBK];
  int t = threadIdx.x, blk = blockIdx.x;
  for (int i = t; i < NBK; i += 256) {
    based[i] = hb[blk * NBK + i] + boffs[i];
    posd[i] = 0;
    bases[i] = hb[(NBLK + blk) * NBK + i] + soffs[i];
    poss[i] = 0;
  }
  __syncthreads();
  int start = blk * chunk, end = min(E, start + chunk);
  for (int i = start + t; i < end; i += 256) {
    int dst = ei[i];
    int src = ei[E + i];
    int bd = dst >> 8, bs = src >> 8;
    int p = atomicAdd(&posd[bd], 1);
    pairs[based[bd] + p] =
        ((unsigned long long)(unsigned)src << 32) | (unsigned)dst;
    int q = atomicAdd(&poss[bs], 1);
    srcb[bases[bs] + q] = (unsigned char)(src & 255);
  }
}

__global__ __launch_bounds__(256)
void k_deg(const unsigned char* __restrict__ srcb, const int* __restrict__ soffs,
           float* __restrict__ dis, int N) {
  __shared__ int h[256];
  int b = blockIdx.x, t = threadIdx.x;
  h[t] = 0;
  __syncthreads();
  int lo = soffs[b], hi = soffs[b + 1];
  for (int i = lo + t; i < hi; i += 256) atomicAdd(&h[srcb[i]], 1);
  __syncthreads();
  int v = (b << 8) + t;
  if (v < N) dis[v] = rsqrtf((float)(h[t] + 1));
}

__global__ __launch_bounds__(256)
void k_fscatter(const unsigned long long* __restrict__ pairs,
                const int* __restrict__ boffs,
                int* __restrict__ offs, int* __restrict__ srcs, int N) {
  __shared__ int h[256], sc[256], cur[256];
  int b = blockIdx.x, t = threadIdx.x;
  h[t] = 0;
  __syncthreads();
  int pl = boffs[b], ph = boffs[b + 1];
  for (int i = pl + t; i < ph; i += 256)
    atomicAdd(&h[(int)(pairs[i] & 255ull)], 1);
  __syncthreads();
  sc[t] = h[t];
  __syncthreads();
  for (int off = 1; off < 256; off <<= 1) {
    int x = (t >= off) ? sc[t - off] : 0;
    __syncthreads();
    sc[t] += x;
    __syncthreads();
  }
  int excl = sc[t] - h[t];
  int v = (b << 8) + t;
  if (v < N) offs[v] = pl + excl;
  cur[t] = pl + excl;
  __syncthreads();
  for (int i = pl + t; i < ph; i += 256) {
    unsigned long long pk = pairs[i];
    int p = atomicAdd(&cur[(int)(pk & 255ull)], 1);
    srcs[p] = (int)(unsigned)(pk >> 32);
  }
}

// W (128x128 fp32 row-major, W[k][c]) -> Wt fp16 transposed: Wt[c][k]
__global__ void k_prepw(const float* __restrict__ W0, const float* __restrict__ W1,
                        const float* __restrict__ W2, _Float16* __restrict__ Wt) {
  int i = blockIdx.x * blockDim.x + threadIdx.x;   // 0..49151
  int m = i >> 14;
  int j = i & 16383;
  int c = j >> 7, k = j & 127;
  const float* W = (m == 0) ? W0 : (m == 1) ? W1 : W2;
  Wt[i] = (_Float16)W[k * 128 + c];
}

// ---------------- fp16 MFMA GEMM + dis-scale epilogue ----------------
// hws is SLICE-MAJOR: hws[sl][v][16 feats], sl = feature/16, slice stride N*16
// halves (3.2 MB contiguous) -> each slice is L2-resident on one XCD in agg.

#define LDH 136   // padded halves per row -> conflict-free ds_read_b128

__global__ __launch_bounds__(256, 2)
void k_gemm(const float* __restrict__ in, int in_stride, int do_relu,
            const _Float16* __restrict__ Wt_g, const float* __restrict__ dis,
            _Float16* __restrict__ hws, int N) {
  __shared__ _Float16 Wt[128 * LDH];
  int t = threadIdx.x;
  int rbase = blockIdx.x * 128;
  size_t slst = (size_t)N * 16;   // slice stride in halves

#pragma unroll
  for (int i = 0; i < 8; ++i) {
    int s = t + i * 256;
    int c = s >> 4, kh = s & 15;
    half8 w = ((const half8*)Wt_g)[s];
    *(half8*)&Wt[c * LDH + kh * 8] = w;
  }
  __syncthreads();

  int wv = t >> 6, lane = t & 63;
  int r0 = wv * 32;
  int lr = lane & 15, lg = lane >> 4;

  f4 acc[2][8];
#pragma unroll
  for (int fm = 0; fm < 2; ++fm)
#pragma unroll
    for (int fn = 0; fn < 8; ++fn) acc[fm][fn] = (f4){0.f, 0.f, 0.f, 0.f};

#pragma unroll
  for (int ks = 0; ks < 4; ++ks) {
    int k0 = ks * 32 + lg * 8;
    half8 a[8];
#pragma unroll
    for (int fn = 0; fn < 8; ++fn)
      a[fn] = *(const half8*)&Wt[(fn * 16 + lr) * LDH + k0];
#pragma unroll
    for (int fm = 0; fm < 2; ++fm) {
      int gr = rbase + r0 + fm * 16 + lr;
      float4 v0 = make_float4(0.f, 0.f, 0.f, 0.f);
      float4 v1 = make_float4(0.f, 0.f, 0.f, 0.f);
      if (gr < N) {
        const float* pr = in + (size_t)gr * in_stride + k0;
        v0 = *(const float4*)pr;
        v1 = *(const float4*)(pr + 4);
      }
      if (do_relu) {
        v0.x = fmaxf(v0.x, 0.f); v0.y = fmaxf(v0.y, 0.f);
        v0.z = fmaxf(v0.z, 0.f); v0.w = fmaxf(v0.w, 0.f);
        v1.x = fmaxf(v1.x, 0.f); v1.y = fmaxf(v1.y, 0.f);
        v1.z = fmaxf(v1.z, 0.f); v1.w = fmaxf(v1.w, 0.f);
      }
      half8 b;
      b[0] = (_Float16)v0.x; b[1] = (_Float16)v0.y;
      b[2] = (_Float16)v0.z; b[3] = (_Float16)v0.w;
      b[4] = (_Float16)v1.x; b[5] = (_Float16)v1.y;
      b[6] = (_Float16)v1.z; b[7] = (_Float16)v1.w;
#pragma unroll
      for (int fn = 0; fn < 8; ++fn)
        acc[fm][fn] = __builtin_amdgcn_mfma_f32_16x16x32_f16(a[fn], b, acc[fm][fn], 0, 0, 0);
    }
  }

#pragma unroll
  for (int fm = 0; fm < 2; ++fm) {
    int gr = rbase + r0 + fm * 16 + lr;
    if (gr >= N) continue;
    float dv = dis[gr];
#pragma unroll
    for (int fn = 0; fn < 8; ++fn) {
      f4 d = acc[fm][fn];
      half4 hv;
      hv[0] = (_Float16)(d[0] * dv);
      hv[1] = (_Float16)(d[1] * dv);
      hv[2] = (_Float16)(d[2] * dv);
      hv[3] = (_Float16)(d[3] * dv);
      *(half4*)(hws + (size_t)fn * slst + (size_t)gr * 16 + lg * 4) = hv;
    }
  }
}

// ---------------- aggregation: feature-sliced, XCD-affine, work-stealing ----
// Each block picks slice = its XCC_ID (locality HINT; per-slice chunk counters
// guarantee exact coverage regardless of placement). Slice (3.2 MB) stays
// resident in that XCD's 4MB L2; srcs/offs streamed with nontemporal loads;
// out written with nontemporal stores so streams don't evict the slice.
#define AGG_CHUNK 256

__global__ __launch_bounds__(256)
void k_agg2(const _Float16* __restrict__ hws, const int* __restrict__ offs,
            const int* __restrict__ srcs, const float* __restrict__ dis,
            const float* __restrict__ bias, float* __restrict__ out,
            int N, int layer, int* __restrict__ ctr) {
  __shared__ int scur;
  int t = threadIdx.x;
  int myx;
  asm volatile("s_getreg_b32 %0, hwreg(HW_REG_XCC_ID)" : "=s"(myx));
  myx &= 7;
  int nchunks = (N + AGG_CHUNK - 1) / AGG_CHUNK;
  size_t slst = (size_t)N * 16;

  for (int rr = 0; rr < 8; ++rr) {
    int sl = (myx + rr) & 7;
    const _Float16* hsl = hws + (size_t)sl * slst;
    int f0 = sl * 16;
    for (;;) {
      if (t == 0) scur = atomicAdd(&ctr[sl], 1);
      __syncthreads();
      int c = scur;
      __syncthreads();
      if (c >= nchunks) break;
      int v = c * AGG_CHUNK + t;
      if (v >= N) continue;

      // self term (hws rows already scaled by dis[src])
      const half8* vp = (const half8*)(hsl + (size_t)v * 16);
      half8 a0 = vp[0], a1 = vp[1];
      float acc[16];
#pragma unroll
      for (int i = 0; i < 8; ++i) { acc[i] = (float)a0[i]; acc[8 + i] = (float)a1[i]; }

      int e0 = __builtin_nontemporal_load(&offs[v]);
      int e1 = __builtin_nontemporal_load(&offs[v + 1]);
      int e = e0;
      for (; e + 4 <= e1; e += 4) {
        int s0 = __builtin_nontemporal_load(&srcs[e + 0]);
        int s1 = __builtin_nontemporal_load(&srcs[e + 1]);
        int s2 = __builtin_nontemporal_load(&srcs[e + 2]);
        int s3 = __builtin_nontemporal_load(&srcs[e + 3]);
        const half8* p0 = (const half8*)(hsl + (size_t)s0 * 16);
        const half8* p1 = (const half8*)(hsl + (size_t)s1 * 16);
        const half8* p2 = (const half8*)(hsl + (size_t)s2 * 16);
        const half8* p3 = (const half8*)(hsl + (size_t)s3 * 16);
        half8 x0 = p0[0], y0 = p0[1];
        half8 x1 = p1[0], y1 = p1[1];
        half8 x2 = p2[0], y2 = p2[1];
        half8 x3 = p3[0], y3 = p3[1];
#pragma unroll
        for (int i = 0; i < 8; ++i) {
          acc[i]     += (float)x0[i] + (float)x1[i] + (float)x2[i] + (float)x3[i];
          acc[8 + i] += (float)y0[i] + (float)y1[i] + (float)y2[i] + (float)y3[i];
        }
      }
      for (; e < e1; ++e) {
        int s = __builtin_nontemporal_load(&srcs[e]);
        const half8* ps = (const half8*)(hsl + (size_t)s * 16);
        half8 x = ps[0], y = ps[1];
#pragma unroll
        for (int i = 0; i < 8; ++i) {
          acc[i] += (float)x[i];
          acc[8 + i] += (float)y[i];
        }
      }

      float dv = dis[v];
      const f4* bp = (const f4*)(bias + f0);
      f4* op = (f4*)(out + (size_t)v * 384 + layer * 128 + f0);
#pragma unroll
      for (int q = 0; q < 4; ++q) {
        f4 bb = bp[q];
        f4 oo;
        oo[0] = fmaf(dv, acc[q * 4 + 0], bb[0]);
        oo[1] = fmaf(dv, acc[q * 4 + 1], bb[1]);
        oo[2] = fmaf(dv, acc[q * 4 + 2], bb[2]);
        oo[3] = fmaf(dv, acc[q * 4 + 3], bb[3]);
        __builtin_nontemporal_store(oo, op + q);
      }
    }
  }
}

// ---------------- launch ----------------

extern "C" void kernel_launch(void* const* d_in, const int* in_sizes, int n_in,
                              void* d_out, int out_size, void* d_ws, size_t ws_size,
                              hipStream_t stream) {
  const float* x  = (const float*)d_in[0];
  const int*   ei = (const int*)d_in[1];
  const float* W0 = (const float*)d_in[2];
  const float* b0 = (const float*)d_in[3];
  const float* W1 = (const float*)d_in[4];
  const float* b1 = (const float*)d_in[5];
  const float* W2 = (const float*)d_in[6];
  const float* b2 = (const float*)d_in[7];
  float* out = (float*)d_out;

  int N = in_sizes[0] / 128;
  int E = in_sizes[1] / 2;
  int nb = (N + 255) >> 8;                       // active buckets
  int chunk = (((E + NBLK - 1) / NBLK) + 255) & ~255;

  char* p = (char*)d_ws;
  auto alloc = [&](size_t sz) { char* r = p; p += (sz + 255) & ~(size_t)255; return r; };
  _Float16* hws  = (_Float16*)alloc((size_t)N * 128 * 2);
  float* dis     = (float*)alloc((size_t)N * 4);
  int*   offs    = (int*)alloc((size_t)(N + 1) * 4);
  int*   srcs    = (int*)alloc((size_t)E * 4);
  _Float16* Wt   = (_Float16*)alloc((size_t)3 * 128 * 128 * 2);
  int*   hb      = (int*)alloc((size_t)2 * NBLK * NBK * 4);
  int*   totals  = (int*)alloc((size_t)2 * NBK * 4);
  int*   boffs   = (int*)alloc((size_t)(NBK + 1) * 4);
  int*   soffs   = (int*)alloc((size_t)(NBK + 1) * 4);
  unsigned long long* pairs = (unsigned long long*)alloc((size_t)E * 8);
  unsigned char* srcb = (unsigned char*)alloc((size_t)E);
  int*   ctrs    = (int*)alloc(24 * 4);

  k_bhist<<<NBLK, 256, 0, stream>>>(ei, E, chunk, hb);
  k_colscan<<<8, 256, 0, stream>>>(hb, totals);
  k_bscan2<<<1, 1024, 0, stream>>>(totals, boffs, soffs, offs, ctrs, N, E);
  k_bscatter<<<NBLK, 256, 0, stream>>>(ei, E, chunk, hb, boffs, soffs, pairs, srcb);
  k_deg<<<nb, 256, 0, stream>>>(srcb, soffs, dis, N);
  k_fscatter<<<nb, 256, 0, stream>>>(pairs, boffs, offs, srcs, N);
  k_prepw<<<192, 256, 0, stream>>>(W0, W1, W2, Wt);

  int gG = (N + 127) / 128;

  // layer 0
  k_gemm<<<gG, 256, 0, stream>>>(x, 128, 0, Wt, dis, hws, N);
  k_agg2<<<2048, 256, 0, stream>>>(hws, offs, srcs, dis, b0, out, N, 0, ctrs);
  // layer 1: input = relu(out[:,0,:]) (stride 384)
  k_gemm<<<gG, 256, 0, stream>>>(out, 384, 1, Wt + 16384, dis, hws, N);
  k_agg2<<<2048, 256, 0, stream>>>(hws, offs, srcs, dis, b1, out, N, 1, ctrs + 8);
  // layer 2: input = relu(out[:,1,:])
  k_gemm<<<gG, 256, 0, stream>>>(out + 128, 384, 1, Wt + 32768, dis, hws, N);
  k_agg2<<<2048, 256, 0, stream>>>(hws, offs, srcs, dis, b2, out, N, 2, ctrs + 16);
}